// Round 8
// baseline (120.934 us; speedup 1.0000x reference)
//
#include <hip/hip_runtime.h>

// AdjGAT: V=20000, D=256, K=16, O=128, H=4.
// Math: attn[h,v] = x[v].(W_h a_h);  out[v] = relu( (1/H)[ sum_h (sum_k c_hk x[nbr_k]).W_h + sum_h b_h ] )
// R17 (from R16=116.1us): overlap gat's serial latency chains.
//  1. gat dual-barrier split: write sidx_s -> barrier1 -> issue FIRST 4 gather
//     rows + attn4 random load together -> softmax shuffles run while both in
//     flight -> barrier2 -> P2 consumes prefetched rows. (Single-barrier form
//     serialized: attn4 load ~600cy -> softmax -> barrier -> gather ~600cy.)
//  2. bias loads hoisted above P3 MFMA loop (in flight through 64 MFMAs).
//  3. K1 xh copy widened to 32B/lane (2 rows/wave, half the copy blocks).
// Established: gather wall ~33-36us = L3 service of 164MB logical (xh 10.2MB >
// 4MB/XCD L2); fill 44.6us fixed; gaps ~26us for 3 dependent dispatches;
// fp8 gather fails err budget; cooperative launch poisons caches (R13);
// packed-fp16 P2 accum verified (R15/R16, absmax 0.00195).
// Pipeline (3 launches):
//   K1 prep_all: blocks 0-63 Wt B-frags | 64-67 wt=W.a | 68+ xh=fp16(x)
//   K2 attn:     attn4[v][h] = xh[v].wt[h]  (dot + shuffle reduce)
//   K3 gat:      P1a sidx | P2a prefetch | P1b softmax | P2b aggregate ->
//                XOR-swizzled LDS A-frags | P3 pipelined B-stream + 64 MFMAs
// ws: attn4 0.32MB | xh 10.24MB | Wt 0.26MB | wt 4KB  (~10.8MB)

#define V_N 20000
#define D_N 256
#define K_N 16
#define O_N 128
#define H_N 4
#define NEG_INF -1e9f
#define TM 16            // nodes per block; V = 1250 * 16

typedef _Float16 f16x8 __attribute__((ext_vector_type(8)));
typedef _Float16 f16x4 __attribute__((ext_vector_type(4)));
typedef float    f32x4 __attribute__((ext_vector_type(4)));

// ---------------- K1: Wt B-frag swizzle + wtilde + xh copy (independent) ----
__global__ __launch_bounds__(256) void prep_all_kernel(
    const float* __restrict__ W, const float* __restrict__ a,
    const float* __restrict__ x,
    _Float16* __restrict__ Wt, float* __restrict__ wt,
    _Float16* __restrict__ xh)
{
    if (blockIdx.x >= 68) {
        // xh copy: wave = two 1KB rows; lane = 32B (two float4) chunk of a row
        const int wid  = threadIdx.x >> 6;
        const int lane = threadIdx.x & 63;
        const int v    = (blockIdx.x - 68) * 8 + wid * 2 + (lane >> 5);
        const int c    = (lane & 31) * 8;
        const float4 p0 = *(const float4*)&x[(size_t)v * D_N + c];
        const float4 p1 = *(const float4*)&x[(size_t)v * D_N + c + 4];
        f16x8 hv = { (_Float16)p0.x, (_Float16)p0.y, (_Float16)p0.z, (_Float16)p0.w,
                     (_Float16)p1.x, (_Float16)p1.y, (_Float16)p1.z, (_Float16)p1.w };
        *(f16x8*)&xh[(size_t)v * D_N + c] = hv;
    } else if (blockIdx.x < 64) {
        const int idx  = blockIdx.x * 256 + threadIdx.x;  // 16384 frag-lane slots
        const int lane = idx & 63;
        const int nt   = (idx >> 6) & 7;    // col tile (16 cols)
        const int s    = (idx >> 9) & 7;    // k slice (32 chans)
        const int h    = idx >> 12;
        const int o    = nt * 16 + (lane & 15);
        const int d0   = s * 32 + (lane >> 4) * 8;
        f16x8 v;
        #pragma unroll
        for (int j = 0; j < 8; ++j)
            v[j] = (_Float16)W[((size_t)h * D_N + d0 + j) * O_N + o];
        *(f16x8*)&Wt[(size_t)idx * 8] = v;
    } else {
        const int h = blockIdx.x - 64;
        const int d = threadIdx.x;
        const float* Wrow = W + ((size_t)h * D_N + d) * O_N;
        const float* ah   = a + h * O_N;
        float s = 0.f;
        #pragma unroll
        for (int o = 0; o < O_N; o += 4) {
            const float4 wv = *(const float4*)&Wrow[o];
            const float4 av = *(const float4*)&ah[o];
            s = fmaf(wv.x, av.x, s); s = fmaf(wv.y, av.y, s);
            s = fmaf(wv.z, av.z, s); s = fmaf(wv.w, av.w, s);
        }
        wt[h * D_N + d] = s;
    }
}

// ---------------- K2: attn logits from fp16 xh ----------------
__global__ __launch_bounds__(256) void attn_kernel(
    const _Float16* __restrict__ xh, const float* __restrict__ wt,
    float* __restrict__ attn4)
{
    const int wid  = threadIdx.x >> 6;
    const int lane = threadIdx.x & 63;
    const int v    = blockIdx.x * 4 + wid;

    const f16x4 hv = *(const f16x4*)&xh[(size_t)v * D_N + lane * 4];
    const float p0 = (float)hv[0], p1 = (float)hv[1],
                p2 = (float)hv[2], p3 = (float)hv[3];

    float s[H_N];
    #pragma unroll
    for (int h = 0; h < H_N; ++h) {
        const float4 w = *(const float4*)&wt[h * D_N + lane * 4];
        float t = fmaf(p0, w.x, 0.f);
        t = fmaf(p1, w.y, t); t = fmaf(p2, w.z, t); t = fmaf(p3, w.w, t);
        s[h] = t;
    }
    #pragma unroll
    for (int h = 0; h < H_N; ++h)
        #pragma unroll
        for (int dd = 32; dd >= 1; dd >>= 1)
            s[h] += __shfl_xor(s[h], dd);
    if (lane == 0)
        *(float4*)&attn4[(size_t)v * 4] = make_float4(s[0], s[1], s[2], s[3]);
}

// ---------------- K3: fused softmax + row-gather + full-K fp16 MFMA ---------
__global__ __launch_bounds__(256, 4) void gat_kernel(
    const _Float16* __restrict__ xh, const float* __restrict__ attn4,
    const _Float16* __restrict__ Wt, const float* __restrict__ b,
    const int* __restrict__ adj, const int* __restrict__ mask_p,
    float* __restrict__ out)
{
    const int v0  = blockIdx.x * TM;
    const int tid = threadIdx.x;
    const int wid  = tid >> 6;
    const int lane = tid & 63;
    const int mask = mask_p[0];

    __shared__ int      sidx_s[TM][17];          // +1 pad
    __shared__ float    coefs_s[K_N][17][H_N];   // [k][node(+pad)][h]
    // yl slot (f16x8 units): h*512 + n*32 + (sl ^ n); sl = 16B slot of row
    __shared__ _Float16 yl[H_N * 512 * 8];       // 32KB

    // B-frag prefetch for P3 (no LDS dependency; drains at barrier1, early)
    const _Float16* Wb = Wt + (size_t)lane * 8 + (size_t)wid * 1024;
    f16x8 cb0 = *(const f16x8*)&Wb[0];
    f16x8 cb1 = *(const f16x8*)&Wb[512];

    // P2 lane geometry (needed for prefetch between barriers)
    const int hw  = lane >> 5;         // half-wave selects node parity
    const int sl  = lane & 31;         // 16B slot within the 512B row
    const int ln0 = wid * 4 + hw;      // i=0 node
    const int ln1 = wid * 4 + 2 + hw;  // i=1 node
    const _Float16* xsl = xh + sl * 8;

    // ---- P1a: indices only, thread = (node, k) ----
    const int node = tid >> 4;
    const int k    = tid & 15;
    const int idx  = adj[(v0 + node) * K_N + k];
    const bool pad = (idx >= mask);
    const int safe = pad ? 0 : idx;
    sidx_s[node][k] = safe;
    __syncthreads();                   // barrier1: sidx_s visible

    // ---- P2a: issue first 2 k-iters' gather rows (4 loads in flight) ----
    const f16x8 pf00 = *(const f16x8*)&xsl[(size_t)sidx_s[ln0][0] * D_N];
    const f16x8 pf01 = *(const f16x8*)&xsl[(size_t)sidx_s[ln1][0] * D_N];
    const f16x8 pf10 = *(const f16x8*)&xsl[(size_t)sidx_s[ln0][1] * D_N];
    const f16x8 pf11 = *(const f16x8*)&xsl[(size_t)sidx_s[ln1][1] * D_N];

    // ---- P1b: softmax coefs (attn4 load + shuffles overlap the prefetch) ----
    {
        const float4 av = *(const float4*)&attn4[(size_t)safe * 4];
        const float lg[H_N] = { pad ? NEG_INF : av.x, pad ? NEG_INF : av.y,
                                pad ? NEG_INF : av.z, pad ? NEG_INF : av.w };
        float c[H_N];
        #pragma unroll
        for (int h = 0; h < H_N; ++h) {
            float m = lg[h];
            #pragma unroll
            for (int s = 8; s >= 1; s >>= 1)
                m = fmaxf(m, __shfl_xor(m, s, 16));
            const float e = pad ? 0.f : __expf(lg[h] - m);
            float sum = e;
            #pragma unroll
            for (int s = 8; s >= 1; s >>= 1)
                sum += __shfl_xor(sum, s, 16);
            // pad coef 0 == ref (exp(-1e9-m)==0); all-pad row -> y=0 -> relu(bbar)
            c[h] = pad ? 0.f : e / sum;
        }
        *(float4*)&coefs_s[k][node][0] = make_float4(c[0], c[1], c[2], c[3]);
    }
    __syncthreads();                   // barrier2: coefs visible, pf drained

    // ---- P2b: weighted aggregate, packed fp16 (v_pk_fma_f16) ----
    {
        f16x8 y[2][H_N];               // node = wid*4 + 2*i + hw
        #pragma unroll
        for (int i = 0; i < 2; ++i)
            #pragma unroll
            for (int h = 0; h < H_N; ++h)
                #pragma unroll
                for (int j = 0; j < 8; ++j) y[i][h][j] = (_Float16)0.f;

        // consume prefetched k=0,1
        #pragma unroll
        for (int kk = 0; kk < 2; ++kk) {
            const f16x8 xv0 = kk ? pf10 : pf00;
            const f16x8 xv1 = kk ? pf11 : pf01;
            const float4 c0 = *(const float4*)&coefs_s[kk][ln0][0];
            const float4 c1 = *(const float4*)&coefs_s[kk][ln1][0];
            y[0][0] += xv0 * (_Float16)c0.x;  y[1][0] += xv1 * (_Float16)c1.x;
            y[0][1] += xv0 * (_Float16)c0.y;  y[1][1] += xv1 * (_Float16)c1.y;
            y[0][2] += xv0 * (_Float16)c0.z;  y[1][2] += xv1 * (_Float16)c1.z;
            y[0][3] += xv0 * (_Float16)c0.w;  y[1][3] += xv1 * (_Float16)c1.w;
        }
        // remaining k = 2..15
        #pragma unroll
        for (int kk = 2; kk < K_N; ++kk) {
            #pragma unroll
            for (int i = 0; i < 2; ++i) {
                const int n  = wid * 4 + 2 * i + hw;
                const int si = sidx_s[n][kk];
                const f16x8 xv = *(const f16x8*)&xsl[(size_t)si * D_N];
                const float4 c = *(const float4*)&coefs_s[kk][n][0];
                y[i][0] += xv * (_Float16)c.x;
                y[i][1] += xv * (_Float16)c.y;
                y[i][2] += xv * (_Float16)c.z;
                y[i][3] += xv * (_Float16)c.w;
            }
        }
        // store fp16 A-fragments, XOR-swizzled (write: contiguous permuted 512B)
        #pragma unroll
        for (int i = 0; i < 2; ++i) {
            const int n    = wid * 4 + 2 * i + hw;
            const int slot = n * 32 + (sl ^ n);
            #pragma unroll
            for (int h = 0; h < H_N; ++h)
                *(f16x8*)&yl[(size_t)(h * 512 + slot) * 8] = y[i][h];
        }
    }
    __syncthreads();

    // ---- epilogue bias prefetch (in flight through the MFMA loop) ----
    const int m = lane & 15;              // node / C col
    const int q = lane >> 4;              // k-group / C row group
    const int col0 = (wid * 2 + 0) * 16 + m;
    const int col1 = (wid * 2 + 1) * 16 + m;
    const float bb0 = b[col0] + b[O_N + col0] + b[2 * O_N + col0] + b[3 * O_N + col0];
    const float bb1 = b[col1] + b[O_N + col1] + b[2 * O_N + col1] + b[3 * O_N + col1];

    // ---- P3: col tiles wid*2, wid*2+1; rotated pipeline over f = h*8+s ----
    f32x4 acc0 = (f32x4){0.f, 0.f, 0.f, 0.f};
    f32x4 acc1 = (f32x4){0.f, 0.f, 0.f, 0.f};
    #pragma unroll
    for (int f = 0; f < 32; ++f) {
        f16x8 nb0, nb1;
        if (f < 31) {
            nb0 = *(const f16x8*)&Wb[(size_t)(f + 1) * 4096];
            nb1 = *(const f16x8*)&Wb[(size_t)(f + 1) * 4096 + 512];
        }
        const int h    = f >> 3;
        const int s    = f & 7;
        const int slot = m * 32 + ((s * 4 + q) ^ m);
        const f16x8 af = *(const f16x8*)&yl[(size_t)(h * 512 + slot) * 8];
        acc0 = __builtin_amdgcn_mfma_f32_16x16x32_f16(af, cb0, acc0, 0, 0, 0);
        acc1 = __builtin_amdgcn_mfma_f32_16x16x32_f16(af, cb1, acc1, 0, 0, 0);
        cb0 = nb0; cb1 = nb1;
    }

    // ---- epilogue: mean heads + mean bias + relu; C: col=m, row=q*4+r ----
    #pragma unroll
    for (int r = 0; r < 4; ++r) {
        const int nodeo = q * 4 + r;
        out[(size_t)(v0 + nodeo) * O_N + col0] = fmaxf(0.25f * (acc0[r] + bb0), 0.f);
        out[(size_t)(v0 + nodeo) * O_N + col1] = fmaxf(0.25f * (acc1[r] + bb1), 0.f);
    }
}

extern "C" void kernel_launch(void* const* d_in, const int* in_sizes, int n_in,
                              void* d_out, int out_size, void* d_ws, size_t ws_size,
                              hipStream_t stream) {
    const float* x      = (const float*)d_in[0];
    const float* W      = (const float*)d_in[1];
    const float* a      = (const float*)d_in[2];
    const float* b      = (const float*)d_in[3];
    const int*   adj    = (const int*)d_in[4];
    const int*   mask_p = (const int*)d_in[5];
    float*       out    = (float*)d_out;

    // ws layout (bytes)
    char* p = (char*)d_ws;
    float*    attn4 = (float*)p;                     //    320,000
    _Float16* xh    = (_Float16*)(p + 320000);       // 10,240,000
    _Float16* Wt    = (_Float16*)(p + 10560000);     //    262,144
    float*    wt    = (float*)(p + 10822144);        //      4,096  (~10.8MB)

    prep_all_kernel<<<68 + V_N / 8, 256, 0, stream>>>(W, a, x, Wt, wt, xh);
    attn_kernel<<<V_N / 4, 256, 0, stream>>>(xh, wt, attn4);
    gat_kernel<<<V_N / TM, 256, 0, stream>>>(xh, attn4, Wt, b, adj, mask_p, out);
}

// Round 9
// 116.362 us; speedup vs baseline: 1.0393x; 1.0393x over previous
//
#include <hip/hip_runtime.h>

// AdjGAT: V=20000, D=256, K=16, O=128, H=4.
// Math: attn[h,v] = x[v].(W_h a_h);  out[v] = relu( (1/H)[ sum_h (sum_k c_hk x[nbr_k]).W_h + sum_h b_h ] )
// R18 = revert to R16 (116.1us, best verified) after R17's dual-barrier split
// regressed (+4.8us: 3rd barrier + attn4 load delayed behind barrier1 + longer
// cb live ranges). Keeps only R17's safe K1 widened copy (32B/lane).
// Established budget: 116 = 44.6 fill (fixed) + ~26 gaps (3 dependent
// dispatches = structural floor; cooperative poisons caches, R13) + ~45 kernel
// work at measured floors (gather wall ~33-36us = L3 service of 164MB logical,
// xh 10.2MB > 4MB/XCD L2; K1 ~6us HBM floor; K2 ~3us).
// Pipeline (3 launches):
//   K1 prep_all: blocks 0-63 Wt B-frags | 64-67 wt=W.a | 68+ xh=fp16(x)
//   K2 attn:     attn4[v][h] = xh[v].wt[h]  (dot + shuffle reduce)
//   K3 gat:      P1 softmax coefs | P2 packed-fp16 gather-aggregate ->
//                XOR-swizzled LDS A-frags | P3 pipelined B-stream + 64 MFMAs
// ws: attn4 0.32MB | xh 10.24MB | Wt 0.26MB | wt 4KB  (~10.8MB)

#define V_N 20000
#define D_N 256
#define K_N 16
#define O_N 128
#define H_N 4
#define NEG_INF -1e9f
#define TM 16            // nodes per block; V = 1250 * 16

typedef _Float16 f16x8 __attribute__((ext_vector_type(8)));
typedef _Float16 f16x4 __attribute__((ext_vector_type(4)));
typedef float    f32x4 __attribute__((ext_vector_type(4)));

// ---------------- K1: Wt B-frag swizzle + wtilde + xh copy (independent) ----
__global__ __launch_bounds__(256) void prep_all_kernel(
    const float* __restrict__ W, const float* __restrict__ a,
    const float* __restrict__ x,
    _Float16* __restrict__ Wt, float* __restrict__ wt,
    _Float16* __restrict__ xh)
{
    if (blockIdx.x >= 68) {
        // xh copy: wave = two 1KB rows; lane = 32B (two float4) chunk of a row
        const int wid  = threadIdx.x >> 6;
        const int lane = threadIdx.x & 63;
        const int v    = (blockIdx.x - 68) * 8 + wid * 2 + (lane >> 5);
        const int c    = (lane & 31) * 8;
        const float4 p0 = *(const float4*)&x[(size_t)v * D_N + c];
        const float4 p1 = *(const float4*)&x[(size_t)v * D_N + c + 4];
        f16x8 hv = { (_Float16)p0.x, (_Float16)p0.y, (_Float16)p0.z, (_Float16)p0.w,
                     (_Float16)p1.x, (_Float16)p1.y, (_Float16)p1.z, (_Float16)p1.w };
        *(f16x8*)&xh[(size_t)v * D_N + c] = hv;
    } else if (blockIdx.x < 64) {
        const int idx  = blockIdx.x * 256 + threadIdx.x;  // 16384 frag-lane slots
        const int lane = idx & 63;
        const int nt   = (idx >> 6) & 7;    // col tile (16 cols)
        const int s    = (idx >> 9) & 7;    // k slice (32 chans)
        const int h    = idx >> 12;
        const int o    = nt * 16 + (lane & 15);
        const int d0   = s * 32 + (lane >> 4) * 8;
        f16x8 v;
        #pragma unroll
        for (int j = 0; j < 8; ++j)
            v[j] = (_Float16)W[((size_t)h * D_N + d0 + j) * O_N + o];
        *(f16x8*)&Wt[(size_t)idx * 8] = v;
    } else {
        const int h = blockIdx.x - 64;
        const int d = threadIdx.x;
        const float* Wrow = W + ((size_t)h * D_N + d) * O_N;
        const float* ah   = a + h * O_N;
        float s = 0.f;
        #pragma unroll
        for (int o = 0; o < O_N; o += 4) {
            const float4 wv = *(const float4*)&Wrow[o];
            const float4 av = *(const float4*)&ah[o];
            s = fmaf(wv.x, av.x, s); s = fmaf(wv.y, av.y, s);
            s = fmaf(wv.z, av.z, s); s = fmaf(wv.w, av.w, s);
        }
        wt[h * D_N + d] = s;
    }
}

// ---------------- K2: attn logits from fp16 xh ----------------
__global__ __launch_bounds__(256) void attn_kernel(
    const _Float16* __restrict__ xh, const float* __restrict__ wt,
    float* __restrict__ attn4)
{
    const int wid  = threadIdx.x >> 6;
    const int lane = threadIdx.x & 63;
    const int v    = blockIdx.x * 4 + wid;

    const f16x4 hv = *(const f16x4*)&xh[(size_t)v * D_N + lane * 4];
    const float p0 = (float)hv[0], p1 = (float)hv[1],
                p2 = (float)hv[2], p3 = (float)hv[3];

    float s[H_N];
    #pragma unroll
    for (int h = 0; h < H_N; ++h) {
        const float4 w = *(const float4*)&wt[h * D_N + lane * 4];
        float t = fmaf(p0, w.x, 0.f);
        t = fmaf(p1, w.y, t); t = fmaf(p2, w.z, t); t = fmaf(p3, w.w, t);
        s[h] = t;
    }
    #pragma unroll
    for (int h = 0; h < H_N; ++h)
        #pragma unroll
        for (int dd = 32; dd >= 1; dd >>= 1)
            s[h] += __shfl_xor(s[h], dd);
    if (lane == 0)
        *(float4*)&attn4[(size_t)v * 4] = make_float4(s[0], s[1], s[2], s[3]);
}

// ---------------- K3: fused softmax + row-gather + full-K fp16 MFMA ---------
__global__ __launch_bounds__(256, 4) void gat_kernel(
    const _Float16* __restrict__ xh, const float* __restrict__ attn4,
    const _Float16* __restrict__ Wt, const float* __restrict__ b,
    const int* __restrict__ adj, const int* __restrict__ mask_p,
    float* __restrict__ out)
{
    const int v0  = blockIdx.x * TM;
    const int tid = threadIdx.x;

    __shared__ int      sidx_s[TM][17];          // +1 pad
    __shared__ float    coefs_s[K_N][17][H_N];   // [k][node(+pad)][h]
    // yl slot (f16x8 units): h*512 + n*32 + (sl ^ n); sl = 32B slot of row
    __shared__ _Float16 yl[H_N * 512 * 8];       // 32KB

    // ---- P1: softmax coefs, thread = (node, k) ----
    {
        const int node = tid >> 4;
        const int k    = tid & 15;
        const int mask = mask_p[0];
        const int idx  = adj[(v0 + node) * K_N + k];
        const bool pad = (idx >= mask);
        const int safe = pad ? 0 : idx;
        const float4 av = *(const float4*)&attn4[(size_t)safe * 4];
        const float lg[H_N] = { pad ? NEG_INF : av.x, pad ? NEG_INF : av.y,
                                pad ? NEG_INF : av.z, pad ? NEG_INF : av.w };
        float c[H_N];
        #pragma unroll
        for (int h = 0; h < H_N; ++h) {
            float m = lg[h];
            #pragma unroll
            for (int s = 8; s >= 1; s >>= 1)
                m = fmaxf(m, __shfl_xor(m, s, 16));
            const float e = pad ? 0.f : __expf(lg[h] - m);
            float sum = e;
            #pragma unroll
            for (int s = 8; s >= 1; s >>= 1)
                sum += __shfl_xor(sum, s, 16);
            // pad coef 0 == ref (exp(-1e9-m)==0); all-pad row -> y=0 -> relu(bbar)
            c[h] = pad ? 0.f : e / sum;
        }
        *(float4*)&coefs_s[k][node][0] = make_float4(c[0], c[1], c[2], c[3]);
        sidx_s[node][k] = safe;
    }
    __syncthreads();

    const int wid  = tid >> 6;
    const int lane = tid & 63;
    // B-frag base for this wave's col tiles (used by prefetch + P3)
    const _Float16* Wb = Wt + (size_t)lane * 8 + (size_t)wid * 1024;

    // ---- P2: row-gather; wave owns nodes [wid*4, wid*4+4), contiguous rows ----
    // Packed fp16 accumulation: y[i][h] is f16x8, FMAs emit v_pk_fma_f16.
    {
        const int hw = lane >> 5;         // half-wave selects node parity
        const int sl = lane & 31;         // 16B slot within the 512B row
        const _Float16* xsl = xh + sl * 8;

        f16x8 y[2][H_N];                  // node = wid*4 + 2*i + hw
        #pragma unroll
        for (int i = 0; i < 2; ++i)
            #pragma unroll
            for (int h = 0; h < H_N; ++h)
                #pragma unroll
                for (int j = 0; j < 8; ++j) y[i][h][j] = (_Float16)0.f;

        #pragma unroll 4
        for (int k = 0; k < K_N; ++k) {
            #pragma unroll
            for (int i = 0; i < 2; ++i) {
                const int n  = wid * 4 + 2 * i + hw;
                const int si = sidx_s[n][k];
                const f16x8 xv = *(const f16x8*)&xsl[(size_t)si * D_N];
                const float4 c = *(const float4*)&coefs_s[k][n][0];
                const _Float16 c0 = (_Float16)c.x, c1 = (_Float16)c.y,
                               c2 = (_Float16)c.z, c3 = (_Float16)c.w;
                y[i][0] += xv * c0;
                y[i][1] += xv * c1;
                y[i][2] += xv * c2;
                y[i][3] += xv * c3;
            }
        }
        // store fp16 A-fragments, XOR-swizzled (write: contiguous permuted 512B)
        #pragma unroll
        for (int i = 0; i < 2; ++i) {
            const int n    = wid * 4 + 2 * i + hw;
            const int slot = n * 32 + (sl ^ n);
            #pragma unroll
            for (int h = 0; h < H_N; ++h)
                *(f16x8*)&yl[(size_t)(h * 512 + slot) * 8] = y[i][h];
        }
    }

    // Pre-barrier B-frag prefetch: issued now, completes during barrier drain.
    f16x8 cb0 = *(const f16x8*)&Wb[0];
    f16x8 cb1 = *(const f16x8*)&Wb[512];
    __syncthreads();

    // ---- P3: col tiles wid*2, wid*2+1; rotated pipeline over f = h*8+s ----
    const int m = lane & 15;              // node / C col
    const int q = lane >> 4;              // k-group / C row group
    f32x4 acc0 = (f32x4){0.f, 0.f, 0.f, 0.f};
    f32x4 acc1 = (f32x4){0.f, 0.f, 0.f, 0.f};
    #pragma unroll
    for (int f = 0; f < 32; ++f) {
        f16x8 nb0, nb1;
        if (f < 31) {
            nb0 = *(const f16x8*)&Wb[(size_t)(f + 1) * 4096];
            nb1 = *(const f16x8*)&Wb[(size_t)(f + 1) * 4096 + 512];
        }
        const int h    = f >> 3;
        const int s    = f & 7;
        const int slot = m * 32 + ((s * 4 + q) ^ m);
        const f16x8 af = *(const f16x8*)&yl[(size_t)(h * 512 + slot) * 8];
        acc0 = __builtin_amdgcn_mfma_f32_16x16x32_f16(af, cb0, acc0, 0, 0, 0);
        acc1 = __builtin_amdgcn_mfma_f32_16x16x32_f16(af, cb1, acc1, 0, 0, 0);
        cb0 = nb0; cb1 = nb1;
    }

    // ---- epilogue: mean heads + mean bias + relu; C: col=m, row=q*4+r ----
    #pragma unroll
    for (int nt = 0; nt < 2; ++nt) {
        const f32x4 acc = nt ? acc1 : acc0;
        const int col = (wid * 2 + nt) * 16 + m;
        const float bb = b[col] + b[O_N + col] + b[2 * O_N + col] + b[3 * O_N + col];
        #pragma unroll
        for (int r = 0; r < 4; ++r) {
            const int node = q * 4 + r;
            out[(size_t)(v0 + node) * O_N + col] = fmaxf(0.25f * (acc[r] + bb), 0.f);
        }
    }
}

extern "C" void kernel_launch(void* const* d_in, const int* in_sizes, int n_in,
                              void* d_out, int out_size, void* d_ws, size_t ws_size,
                              hipStream_t stream) {
    const float* x      = (const float*)d_in[0];
    const float* W      = (const float*)d_in[1];
    const float* a      = (const float*)d_in[2];
    const float* b      = (const float*)d_in[3];
    const int*   adj    = (const int*)d_in[4];
    const int*   mask_p = (const int*)d_in[5];
    float*       out    = (float*)d_out;

    // ws layout (bytes)
    char* p = (char*)d_ws;
    float*    attn4 = (float*)p;                     //    320,000
    _Float16* xh    = (_Float16*)(p + 320000);       // 10,240,000
    _Float16* Wt    = (_Float16*)(p + 10560000);     //    262,144
    float*    wt    = (float*)(p + 10822144);        //      4,096  (~10.8MB)

    prep_all_kernel<<<68 + V_N / 8, 256, 0, stream>>>(W, a, x, Wt, wt, xh);
    attn_kernel<<<V_N / 4, 256, 0, stream>>>(xh, wt, attn4);
    gat_kernel<<<V_N / TM, 256, 0, stream>>>(xh, attn4, Wt, b, adj, mask_p, out);
}